// Round 1
// baseline (1403.934 us; speedup 1.0000x reference)
//
#include <hip/hip_runtime.h>

// GRU-D fused scan, v3: LDS-broadcast h-state.
// R5 diagnosis: v2's critical path was the per-step global h round-trip
// (f16 store -> vmcnt(0) drain -> s_dcache_inv -> s_load L2 refill) plus
// SGPR->VGPR operand moves (VALUBusy 57% @ ~300 VALU/wave/step vs 105 dot2).
// Fix: h0/h1/hx live in LDS; updaters ds_write f16; all waves read their
// K-half via uniform-address ds_read_b128 (same-addr broadcast = conflict-
// free, 19 reads/wave/step vs R3's 105 ds_read_b32 that made LDS the
// bottleneck). Barriers are now lgkmcnt-only, no vmem drains on the chain.
// Partials split into planar float2 arrays (pA=L0 a,c; pB=L1 d,e) to halve
// updater gather cycles (4-way instead of 8-way stride conflicts).

#define BB 256
#define SS 1024
#define DD 32
#define HH 128
#define NT 768

typedef _Float16 f16;
typedef __attribute__((ext_vector_type(2))) _Float16 h2;

__device__ inline h2 as_h2(int x) { union { int i; h2 h; } u; u.i = x; return u.h; }

__device__ inline float dot2(h2 a, h2 b, float c) {
    return __builtin_amdgcn_fdot2(a, b, c, false);
}

__device__ inline float frcp(float x) { return __builtin_amdgcn_rcpf(x); }
__device__ inline float fast_sigm(float x) { return frcp(1.0f + __expf(-x)); }
__device__ inline float fast_tanh(float x) {
    x = fminf(15.0f, fmaxf(-15.0f, x));
    float e = __expf(-2.0f * x);
    return (1.0f - e) * frcp(1.0f + e);
}

struct ImpState { float xprev, tprev; bool hasprev; };

// Wave 0 only (all 64 lanes active in the ballot). Lane l<32 owns feature l.
__device__ inline void impute_store(int i, float xv, int l, ImpState& st,
                                    f16* hxs, const float* tb) {
    bool nanp = (l < 32) && (xv != xv);
    unsigned long long bal = __ballot(nanp);
    bool mask = bal != 0ull;
    if (l < 32) {
        float imp = mask ? st.xprev : xv;
        hxs[l] = (f16)imp;
        if (!mask) st.xprev = xv;
    }
    float tcur = tb[i];
    float tdel = (i == 0) ? 0.0f : (tcur - tb[i - 1]);
    float texp = st.hasprev ? (tcur - st.tprev) : tdel;
    if (l == 32) hxs[32] = (f16)(mask ? 1.0f : 0.0f);
    if (l == 33) hxs[33] = (f16)texp;
    if (!mask) { st.hasprev = true; st.tprev = tcur; }
}

__global__ __launch_bounds__(NT, 3) void gru_fused(
    const float* __restrict__ t_in, const float* __restrict__ x_in,
    const float* __restrict__ Wih0, const float* __restrict__ Whh0,
    const float* __restrict__ bih0, const float* __restrict__ bhh0,
    const float* __restrict__ Wih1, const float* __restrict__ Whh1,
    const float* __restrict__ bih1, const float* __restrict__ bhh1,
    float* __restrict__ out, char* __restrict__ ws)
{
    __shared__ float tb[SS];                  // timestamps (4 KB)
    __shared__ float2 pA[NT];                 // L0 partials (a,c) (6 KB)
    __shared__ float2 pB[NT];                 // L1 partials (d,e) (6 KB)
    __shared__ __align__(16) f16 h0s[HH];     // h0 state (256 B)
    __shared__ __align__(16) f16 h1s[HH];     // h1 state (256 B)
    __shared__ __align__(16) f16 hxs[48];     // imputed input, 34 used (96 B)

    const int tid = threadIdx.x;
    const int b = blockIdx.x;
    const int group = tid >= 384;       // K-half, wave-uniform (waves 0-5 / 6-11)
    const int row = tid - 384 * group;  // gate row 0..383

    // ---- pack this thread's half-rows into registers (f32 -> f16x2) ----
    h2 wih0[9], whh0[32], wih1[32], whh1[32];
    {
        const float* p = Wih0 + row * 34;
        const int lim = 8 + group;      // group0: 8 real pairs (+1 zero pad), group1: 9
        #pragma unroll
        for (int k = 0; k < 9; k++) {
            int e = 16 * group + 2 * k;
            f16 lo = (k < lim) ? (f16)p[e]     : (f16)0.0f;
            f16 hi = (k < lim) ? (f16)p[e + 1] : (f16)0.0f;
            h2 v = {lo, hi}; wih0[k] = v;
        }
        p = Whh0 + row * HH + 64 * group;
        #pragma unroll
        for (int k = 0; k < 32; k++) { h2 v = {(f16)p[2*k], (f16)p[2*k+1]}; whh0[k] = v; }
        p = Wih1 + row * HH + 64 * group;
        #pragma unroll
        for (int k = 0; k < 32; k++) { h2 v = {(f16)p[2*k], (f16)p[2*k+1]}; wih1[k] = v; }
        p = Whh1 + row * HH + 64 * group;
        #pragma unroll
        for (int k = 0; k < 32; k++) { h2 v = {(f16)p[2*k], (f16)p[2*k+1]}; whh1[k] = v; }
    }

    // ---- updater setup: waves 8,9 -> h0 units; waves 10,11 -> h1 units ----
    const bool isU = (tid >= 512);
    const bool isU0 = (tid >= 512 && tid < 640);
    const int j = isU0 ? (tid - 512) : (tid - 640);   // hidden unit (updaters only)
    float ubi[3], ubh[3]; float hr = 0.0f;
    if (isU) {
        const float* bi = isU0 ? bih0 : bih1;
        const float* bh = isU0 ? bhh0 : bhh1;
        #pragma unroll
        for (int q = 0; q < 3; q++) { ubi[q] = bi[j + 128*q]; ubh[q] = bh[j + 128*q]; }
    }

    // ---- prologue: tb, zero state, impute(0) ----
    for (int i2 = tid; i2 < SS; i2 += NT) tb[i2] = t_in[i2];
    if (tid < 64)        ((int*)h0s)[tid]       = 0;
    else if (tid < 128)  ((int*)h1s)[tid - 64]  = 0;
    else if (tid < 152)  ((int*)hxs)[tid - 128] = 0;

    const float* xrow = x_in + (size_t)b * SS * DD + tid;   // deref only tid<32
    ImpState st; st.xprev = 0.0f; st.tprev = 0.0f; st.hasprev = false;

    __syncthreads();
    if (tid < 64) {
        float xv0 = (tid < 32) ? xrow[0] : 0.0f;
        impute_store(0, xv0, tid, st, hxs, tb);
    }
    __syncthreads();

    // wave-uniform LDS bases for this wave's K-half
    const int4* h0v  = (const int4*)(h0s + 64 * group);   // 8x int4 = 64 f16
    const int4* h1v  = (const int4*)(h1s + 64 * group);
    const int4* hxv4 = (const int4*)(hxs + 16 * group);   // 2x int4 = 16 f16
    const int*  hxep = (const int*)(hxs + 32);            // elements 32,33

    for (int i = 0; i <= SS; ++i) {
        const bool doL0 = (i < SS), doL1 = (i > 0), doImp = (i + 1 < SS);

        // prefetch next x row for imputation (overlaps with dot phase)
        float xv_n = 0.0f;
        if (tid < 32 && doImp) xv_n = xrow[(size_t)(i + 1) * DD];

        // ---- dots: h operands via uniform ds_read_b128 broadcast ----
        float aP = 0.0f;
        {
            int4 u0 = hxv4[0], u1 = hxv4[1];
            int he = *hxep;   // group0 pairs with zero weight wih0[8]
            aP = dot2(as_h2(u0.x), wih0[0], aP);
            aP = dot2(as_h2(u0.y), wih0[1], aP);
            aP = dot2(as_h2(u0.z), wih0[2], aP);
            aP = dot2(as_h2(u0.w), wih0[3], aP);
            aP = dot2(as_h2(u1.x), wih0[4], aP);
            aP = dot2(as_h2(u1.y), wih0[5], aP);
            aP = dot2(as_h2(u1.z), wih0[6], aP);
            aP = dot2(as_h2(u1.w), wih0[7], aP);
            aP = dot2(as_h2(he),   wih0[8], aP);
        }
        float cC[4] = {0,0,0,0}, dC[4] = {0,0,0,0}, eC[4] = {0,0,0,0};
        #pragma unroll
        for (int c = 0; c < 8; ++c) {
            int4 v = h0v[c];
            cC[0] = dot2(as_h2(v.x), whh0[4*c+0], cC[0]);
            dC[0] = dot2(as_h2(v.x), wih1[4*c+0], dC[0]);
            cC[1] = dot2(as_h2(v.y), whh0[4*c+1], cC[1]);
            dC[1] = dot2(as_h2(v.y), wih1[4*c+1], dC[1]);
            cC[2] = dot2(as_h2(v.z), whh0[4*c+2], cC[2]);
            dC[2] = dot2(as_h2(v.z), wih1[4*c+2], dC[2]);
            cC[3] = dot2(as_h2(v.w), whh0[4*c+3], cC[3]);
            dC[3] = dot2(as_h2(v.w), wih1[4*c+3], dC[3]);
        }
        #pragma unroll
        for (int c = 0; c < 8; ++c) {
            int4 v = h1v[c];
            eC[0] = dot2(as_h2(v.x), whh1[4*c+0], eC[0]);
            eC[1] = dot2(as_h2(v.y), whh1[4*c+1], eC[1]);
            eC[2] = dot2(as_h2(v.z), whh1[4*c+2], eC[2]);
            eC[3] = dot2(as_h2(v.w), whh1[4*c+3], eC[3]);
        }
        float cP = (cC[0] + cC[1]) + (cC[2] + cC[3]);
        float dP = (dC[0] + dC[1]) + (dC[2] + dC[3]);
        float eP = (eC[0] + eC[1]) + (eC[2] + eC[3]);
        pA[tid] = make_float2(aP, cP);
        pB[tid] = make_float2(dP, eP);
        __syncthreads();   // B1 (lgkm only)

        // ---- update phase ----
        if (isU) {
            bool act = isU0 ? doL0 : doL1;
            if (act) {
                const float2* P = isU0 ? pA : pB;
                float2 q0a = P[j],       q0b = P[384 + j];
                float2 q1a = P[j + 128], q1b = P[384 + j + 128];
                float2 q2a = P[j + 256], q2b = P[384 + j + 256];
                float rx = q0a.x + q0b.x, rh = q0a.y + q0b.y;
                float zx = q1a.x + q1b.x, zh = q1a.y + q1b.y;
                float nx = q2a.x + q2b.x, nh = q2a.y + q2b.y;
                float r = fast_sigm(ubi[0] + ubh[0] + rx + rh);
                float z = fast_sigm(ubi[1] + ubh[1] + zx + zh);
                float n = fast_tanh(ubi[2] + nx + r * (ubh[2] + nh));
                hr = (1.0f - z) * n + z * hr;
                f16* hp = isU0 ? h0s : h1s;
                hp[j] = (f16)hr;          // LDS write, drained at B2
            }
        } else if (tid < 64 && doImp) {
            impute_store(i + 1, xv_n, tid, st, hxs, tb);
        }
        __syncthreads();   // B2 (lgkm only) -> h/hx visible for next iter
    }

    if (tid >= 640) out[(size_t)b * HH + (tid - 640)] = hr;
}

extern "C" void kernel_launch(void* const* d_in, const int* in_sizes, int n_in,
                              void* d_out, int out_size, void* d_ws, size_t ws_size,
                              hipStream_t stream) {
    gru_fused<<<dim3(BB), dim3(NT), 0, stream>>>(
        (const float*)d_in[0], (const float*)d_in[1],
        (const float*)d_in[2], (const float*)d_in[3],
        (const float*)d_in[4], (const float*)d_in[5],
        (const float*)d_in[6], (const float*)d_in[7],
        (const float*)d_in[8], (const float*)d_in[9],
        (float*)d_out, (char*)d_ws);
}

// Round 2
// 1334.448 us; speedup vs baseline: 1.0521x; 1.0521x over previous
//
#include <hip/hip_runtime.h>

// GRU-D fused scan, v4: v3 + pinned register budget.
// R6 diagnosis: v2 AND v3 both allocated only 84 VGPRs (rocprof) while the
// packed weights alone need 104/thread; WRITE_SIZE=45.7MB (= ~238 B/thread)
// with zero global stores in v3 proves scratch spill write-out, and the
// spilled ~60 dwords are reloaded from scratch EVERY step -> ~60 extra VMEM
// + addr VALU per wave per step (VALUBusy 54% @ ~300 VALU/step vs 105 dot2).
// __launch_bounds__(768,3) only sets MIN waves/EU; the RA's occupancy
// heuristic still shrank to the 84-reg (6 waves/EU) tier and spilled.
// Fix: pin amdgpu_waves_per_eu(3,3) -> RA budget 512/3 = 168 regs, weights
// (104) + temps (~40) fit spill-free. No logic changes vs v3.

#define BB 256
#define SS 1024
#define DD 32
#define HH 128
#define NT 768

typedef _Float16 f16;
typedef __attribute__((ext_vector_type(2))) _Float16 h2;

__device__ inline h2 as_h2(int x) { union { int i; h2 h; } u; u.i = x; return u.h; }

__device__ inline float dot2(h2 a, h2 b, float c) {
    return __builtin_amdgcn_fdot2(a, b, c, false);
}

__device__ inline float frcp(float x) { return __builtin_amdgcn_rcpf(x); }
__device__ inline float fast_sigm(float x) { return frcp(1.0f + __expf(-x)); }
__device__ inline float fast_tanh(float x) {
    x = fminf(15.0f, fmaxf(-15.0f, x));
    float e = __expf(-2.0f * x);
    return (1.0f - e) * frcp(1.0f + e);
}

struct ImpState { float xprev, tprev; bool hasprev; };

// Wave 0 only (all 64 lanes active in the ballot). Lane l<32 owns feature l.
__device__ inline void impute_store(int i, float xv, int l, ImpState& st,
                                    f16* hxs, const float* tb) {
    bool nanp = (l < 32) && (xv != xv);
    unsigned long long bal = __ballot(nanp);
    bool mask = bal != 0ull;
    if (l < 32) {
        float imp = mask ? st.xprev : xv;
        hxs[l] = (f16)imp;
        if (!mask) st.xprev = xv;
    }
    float tcur = tb[i];
    float tdel = (i == 0) ? 0.0f : (tcur - tb[i - 1]);
    float texp = st.hasprev ? (tcur - st.tprev) : tdel;
    if (l == 32) hxs[32] = (f16)(mask ? 1.0f : 0.0f);
    if (l == 33) hxs[33] = (f16)texp;
    if (!mask) { st.hasprev = true; st.tprev = tcur; }
}

__global__
__attribute__((amdgpu_flat_work_group_size(NT, NT), amdgpu_waves_per_eu(3, 3)))
void gru_fused(
    const float* __restrict__ t_in, const float* __restrict__ x_in,
    const float* __restrict__ Wih0, const float* __restrict__ Whh0,
    const float* __restrict__ bih0, const float* __restrict__ bhh0,
    const float* __restrict__ Wih1, const float* __restrict__ Whh1,
    const float* __restrict__ bih1, const float* __restrict__ bhh1,
    float* __restrict__ out, char* __restrict__ ws)
{
    __shared__ float tb[SS];                  // timestamps (4 KB)
    __shared__ float2 pA[NT];                 // L0 partials (a,c) (6 KB)
    __shared__ float2 pB[NT];                 // L1 partials (d,e) (6 KB)
    __shared__ __align__(16) f16 h0s[HH];     // h0 state (256 B)
    __shared__ __align__(16) f16 h1s[HH];     // h1 state (256 B)
    __shared__ __align__(16) f16 hxs[48];     // imputed input, 34 used (96 B)

    const int tid = threadIdx.x;
    const int b = blockIdx.x;
    const int group = tid >= 384;       // K-half, wave-uniform (waves 0-5 / 6-11)
    const int row = tid - 384 * group;  // gate row 0..383

    // ---- pack this thread's half-rows into registers (f32 -> f16x2) ----
    h2 wih0[9], whh0[32], wih1[32], whh1[32];
    {
        const float* p = Wih0 + row * 34;
        const int lim = 8 + group;      // group0: 8 real pairs (+1 zero pad), group1: 9
        #pragma unroll
        for (int k = 0; k < 9; k++) {
            int e = 16 * group + 2 * k;
            f16 lo = (k < lim) ? (f16)p[e]     : (f16)0.0f;
            f16 hi = (k < lim) ? (f16)p[e + 1] : (f16)0.0f;
            h2 v = {lo, hi}; wih0[k] = v;
        }
        p = Whh0 + row * HH + 64 * group;
        #pragma unroll
        for (int k = 0; k < 32; k++) { h2 v = {(f16)p[2*k], (f16)p[2*k+1]}; whh0[k] = v; }
        p = Wih1 + row * HH + 64 * group;
        #pragma unroll
        for (int k = 0; k < 32; k++) { h2 v = {(f16)p[2*k], (f16)p[2*k+1]}; wih1[k] = v; }
        p = Whh1 + row * HH + 64 * group;
        #pragma unroll
        for (int k = 0; k < 32; k++) { h2 v = {(f16)p[2*k], (f16)p[2*k+1]}; whh1[k] = v; }
    }

    // ---- updater setup: waves 8,9 -> h0 units; waves 10,11 -> h1 units ----
    const bool isU = (tid >= 512);
    const bool isU0 = (tid >= 512 && tid < 640);
    const int j = isU0 ? (tid - 512) : (tid - 640);   // hidden unit (updaters only)
    float ubi[3], ubh[3]; float hr = 0.0f;
    if (isU) {
        const float* bi = isU0 ? bih0 : bih1;
        const float* bh = isU0 ? bhh0 : bhh1;
        #pragma unroll
        for (int q = 0; q < 3; q++) { ubi[q] = bi[j + 128*q]; ubh[q] = bh[j + 128*q]; }
    }

    // ---- prologue: tb, zero state, impute(0) ----
    for (int i2 = tid; i2 < SS; i2 += NT) tb[i2] = t_in[i2];
    if (tid < 64)        ((int*)h0s)[tid]       = 0;
    else if (tid < 128)  ((int*)h1s)[tid - 64]  = 0;
    else if (tid < 152)  ((int*)hxs)[tid - 128] = 0;

    const float* xrow = x_in + (size_t)b * SS * DD + tid;   // deref only tid<32
    ImpState st; st.xprev = 0.0f; st.tprev = 0.0f; st.hasprev = false;

    __syncthreads();
    if (tid < 64) {
        float xv0 = (tid < 32) ? xrow[0] : 0.0f;
        impute_store(0, xv0, tid, st, hxs, tb);
    }
    __syncthreads();

    // wave-uniform LDS bases for this wave's K-half
    const int4* h0v  = (const int4*)(h0s + 64 * group);   // 8x int4 = 64 f16
    const int4* h1v  = (const int4*)(h1s + 64 * group);
    const int4* hxv4 = (const int4*)(hxs + 16 * group);   // 2x int4 = 16 f16
    const int*  hxep = (const int*)(hxs + 32);            // elements 32,33

    for (int i = 0; i <= SS; ++i) {
        const bool doL0 = (i < SS), doL1 = (i > 0), doImp = (i + 1 < SS);

        // prefetch next x row for imputation (overlaps with dot phase)
        float xv_n = 0.0f;
        if (tid < 32 && doImp) xv_n = xrow[(size_t)(i + 1) * DD];

        // ---- dots: h operands via uniform ds_read_b128 broadcast ----
        float aP = 0.0f;
        {
            int4 u0 = hxv4[0], u1 = hxv4[1];
            int he = *hxep;   // group0 pairs with zero weight wih0[8]
            aP = dot2(as_h2(u0.x), wih0[0], aP);
            aP = dot2(as_h2(u0.y), wih0[1], aP);
            aP = dot2(as_h2(u0.z), wih0[2], aP);
            aP = dot2(as_h2(u0.w), wih0[3], aP);
            aP = dot2(as_h2(u1.x), wih0[4], aP);
            aP = dot2(as_h2(u1.y), wih0[5], aP);
            aP = dot2(as_h2(u1.z), wih0[6], aP);
            aP = dot2(as_h2(u1.w), wih0[7], aP);
            aP = dot2(as_h2(he),   wih0[8], aP);
        }
        float cC[4] = {0,0,0,0}, dC[4] = {0,0,0,0}, eC[4] = {0,0,0,0};
        #pragma unroll
        for (int c = 0; c < 8; ++c) {
            int4 v = h0v[c];
            cC[0] = dot2(as_h2(v.x), whh0[4*c+0], cC[0]);
            dC[0] = dot2(as_h2(v.x), wih1[4*c+0], dC[0]);
            cC[1] = dot2(as_h2(v.y), whh0[4*c+1], cC[1]);
            dC[1] = dot2(as_h2(v.y), wih1[4*c+1], dC[1]);
            cC[2] = dot2(as_h2(v.z), whh0[4*c+2], cC[2]);
            dC[2] = dot2(as_h2(v.z), wih1[4*c+2], dC[2]);
            cC[3] = dot2(as_h2(v.w), whh0[4*c+3], cC[3]);
            dC[3] = dot2(as_h2(v.w), wih1[4*c+3], dC[3]);
        }
        #pragma unroll
        for (int c = 0; c < 8; ++c) {
            int4 v = h1v[c];
            eC[0] = dot2(as_h2(v.x), whh1[4*c+0], eC[0]);
            eC[1] = dot2(as_h2(v.y), whh1[4*c+1], eC[1]);
            eC[2] = dot2(as_h2(v.z), whh1[4*c+2], eC[2]);
            eC[3] = dot2(as_h2(v.w), whh1[4*c+3], eC[3]);
        }
        float cP = (cC[0] + cC[1]) + (cC[2] + cC[3]);
        float dP = (dC[0] + dC[1]) + (dC[2] + dC[3]);
        float eP = (eC[0] + eC[1]) + (eC[2] + eC[3]);
        pA[tid] = make_float2(aP, cP);
        pB[tid] = make_float2(dP, eP);
        __syncthreads();   // B1 (lgkm only)

        // ---- update phase ----
        if (isU) {
            bool act = isU0 ? doL0 : doL1;
            if (act) {
                const float2* P = isU0 ? pA : pB;
                float2 q0a = P[j],       q0b = P[384 + j];
                float2 q1a = P[j + 128], q1b = P[384 + j + 128];
                float2 q2a = P[j + 256], q2b = P[384 + j + 256];
                float rx = q0a.x + q0b.x, rh = q0a.y + q0b.y;
                float zx = q1a.x + q1b.x, zh = q1a.y + q1b.y;
                float nx = q2a.x + q2b.x, nh = q2a.y + q2b.y;
                float r = fast_sigm(ubi[0] + ubh[0] + rx + rh);
                float z = fast_sigm(ubi[1] + ubh[1] + zx + zh);
                float n = fast_tanh(ubi[2] + nx + r * (ubh[2] + nh));
                hr = (1.0f - z) * n + z * hr;
                f16* hp = isU0 ? h0s : h1s;
                hp[j] = (f16)hr;          // LDS write, drained at B2
            }
        } else if (tid < 64 && doImp) {
            impute_store(i + 1, xv_n, tid, st, hxs, tb);
        }
        __syncthreads();   // B2 (lgkm only) -> h/hx visible for next iter
    }

    if (tid >= 640) out[(size_t)b * HH + (tid - 640)] = hr;
}

extern "C" void kernel_launch(void* const* d_in, const int* in_sizes, int n_in,
                              void* d_out, int out_size, void* d_ws, size_t ws_size,
                              hipStream_t stream) {
    gru_fused<<<dim3(BB), dim3(NT), 0, stream>>>(
        (const float*)d_in[0], (const float*)d_in[1],
        (const float*)d_in[2], (const float*)d_in[3],
        (const float*)d_in[4], (const float*)d_in[5],
        (const float*)d_in[6], (const float*)d_in[7],
        (const float*)d_in[8], (const float*)d_in[9],
        (float*)d_out, (char*)d_ws);
}